// Round 3
// baseline (4588.965 us; speedup 1.0000x reference)
//
#include <hip/hip_runtime.h>
#include <hip/hip_bf16.h>
#include <cstdint>

#define Bq 64
#define Pq 196
#define ENCq 2048
#define Aq 512
#define Hq 512
#define Vq 30000
#define Lq 30
#define Tq 29

typedef __bf16 bf16x8 __attribute__((ext_vector_type(8)));
typedef __bf16 bf16x4 __attribute__((ext_vector_type(4)));
typedef float f32x4 __attribute__((ext_vector_type(4)));
typedef __hip_bfloat16 bf16_t;

__device__ __forceinline__ float sigmoidf_(float x){ return 1.0f/(1.0f+expf(-x)); }

// ---------------- sort (stable descending argsort of lengths) ----------------
__global__ void sort_kernel(const int* __restrict__ cap_len, const int* __restrict__ caps,
                            int* __restrict__ sort_ind_i, int* __restrict__ dec_len_i,
                            int* __restrict__ caps_sorted,
                            float* __restrict__ out_caps, float* __restrict__ out_declen,
                            float* __restrict__ out_sortind)
{
    __shared__ int len[Bq];
    __shared__ int sidx[Bq];
    int i = threadIdx.x;
    len[i] = cap_len[i];
    __syncthreads();
    int li = len[i];
    int rank = 0;
    for (int j = 0; j < Bq; j++){
        int lj = len[j];
        rank += (lj > li) || (lj == li && j < i);
    }
    sidx[rank] = i;
    __syncthreads();
    int src = sidx[i];
    sort_ind_i[i] = src;
    int dl = len[src] - 1;
    dec_len_i[i] = dl;
    out_declen[i] = (float)dl;
    out_sortind[i] = (float)src;
    for (int tt = 0; tt < Lq; tt++){
        int cv = caps[src*Lq + tt];
        caps_sorted[i*Lq + tt] = cv;
        out_caps[i*Lq + tt] = (float)cv;
    }
}

// ---------------- pack / convert helpers ----------------
__global__ void cvt_bf16(bf16_t* __restrict__ dst, const float* __restrict__ src, int n)
{
    int i = blockIdx.x*256 + threadIdx.x;
    if (i < n) dst[i] = __float2bfloat16(src[i]);
}

__global__ void pack_rowcat_bf16(bf16_t* __restrict__ dst, const float* __restrict__ a, int na,
                                 const float* __restrict__ b, int nb)
{
    int i = blockIdx.x*256 + threadIdx.x;
    if (i < na) dst[i] = __float2bfloat16(a[i]);
    else if (i < na + nb) dst[i] = __float2bfloat16(b[i - na]);
}

__global__ void pack_rowcat_f32(float* __restrict__ dst, const float* __restrict__ a, int na,
                                const float* __restrict__ b, int nb)
{
    int i = blockIdx.x*256 + threadIdx.x;
    if (i < na) dst[i] = a[i];
    else if (i < na + nb) dst[i] = b[i - na];
}

// gates weight, permuted rows (rp = 4j+g -> r = g*512+j), cols = [W_ih awe-part (2048) | W_hh (512)]
__global__ void pack_wcatg2(bf16_t* __restrict__ dst, const float* __restrict__ wih,
                            const float* __restrict__ whh)
{
    int i = blockIdx.x*256 + threadIdx.x;
    if (i >= 2048*2560) return;
    int rp = i / 2560, c = i % 2560;
    int g = rp & 3, j = rp >> 2;
    int r = g*512 + j;
    float v = (c < 2048) ? wih[(size_t)r*2560 + 512 + c] : whh[(size_t)r*512 + (c - 2048)];
    dst[i] = __float2bfloat16(v);
}

// emb-part of W_ih, permuted rows, K=512
__global__ void pack_wembg(bf16_t* __restrict__ dst, const float* __restrict__ wih)
{
    int i = blockIdx.x*256 + threadIdx.x;
    if (i >= 2048*512) return;
    int rp = i >> 9, c = i & 511;
    int g = rp & 3, j = rp >> 2;
    int r = g*512 + j;
    dst[i] = __float2bfloat16(wih[(size_t)r*2560 + c]);
}

__global__ void biasg_perm_kernel(float* __restrict__ dst, const float* __restrict__ bi,
                                  const float* __restrict__ bh)
{
    int i = blockIdx.x*256 + threadIdx.x;
    if (i >= 2048) return;
    int g = i & 3, j = i >> 2;
    int r = g*512 + j;
    dst[i] = bi[r] + bh[r];
}

// embA row m = t*64 + b  :=  bf16(embed[caps_sorted[b][t]])
__global__ void gather_emb(const float* __restrict__ embed, const int* __restrict__ caps_sorted,
                           bf16_t* __restrict__ embA)
{
    int m = blockIdx.x;            // 0..1855
    int t = m >> 6, b = m & 63;
    int cap = caps_sorted[b*Lq + t];
    const float* er = embed + (size_t)cap*512;
    bf16_t* dr = embA + (size_t)m*512;
    for (int j = threadIdx.x; j < 512; j += 256) dr[j] = __float2bfloat16(er[j]);
}

// ---------------- gather encoder into sorted order, convert to bf16, compute mean ----------------
__global__ __launch_bounds__(256)
void gather_cvt_mean(const float* __restrict__ enc, const int* __restrict__ sort_ind,
                     bf16_t* __restrict__ enc_bf, bf16_t* __restrict__ mean_bf)
{
    int b = blockIdx.x;
    int d = blockIdx.y*256 + threadIdx.x;
    int src = sort_ind[b];
    const float* col = enc + (size_t)src * Pq * ENCq + d;
    bf16_t* dst = enc_bf + (size_t)b * Pq * ENCq + d;
    float s = 0.f;
    for (int p = 0; p < Pq; p++){
        float v = col[(size_t)p*ENCq];
        s += v;
        dst[(size_t)p*ENCq] = __float2bfloat16(v);
    }
    mean_bf[(size_t)b*ENCq + d] = __float2bfloat16(s * (1.0f/196.0f));
}

// ================= h0/c0 GEMM: waves split K, LDS reduce =================
__global__ __launch_bounds__(256)
void hc0_ksplit(const bf16_t* __restrict__ A, const bf16_t* __restrict__ W,
                const float* __restrict__ bias,
                bf16_t* __restrict__ h0, float* __restrict__ c_state)
{
    __shared__ float red[2][64][64];
    const int lane = threadIdx.x & 63;
    const int wave = threadIdx.x >> 6;
    const int mr = lane & 15;
    const int quad = lane >> 4;
    const int n0 = blockIdx.x * 64;
    const int kw = 2048 >> 2;
    const int kbeg = wave * kw;

    const bf16_t* ap[4];
    const bf16_t* bp[4];
    #pragma unroll
    for (int i = 0; i < 4; i++){
        ap[i] = A + (size_t)(i*16 + mr)*2048 + quad*8;
        bp[i] = W + (size_t)(n0 + i*16 + mr)*2048 + quad*8;
    }
    f32x4 zero = {0.f,0.f,0.f,0.f};
    f32x4 acc[4][4];
    #pragma unroll
    for (int i = 0; i < 4; i++)
        #pragma unroll
        for (int j = 0; j < 4; j++) acc[i][j] = zero;

    for (int k = kbeg; k < kbeg + kw; k += 32){
        bf16x8 a[4], b[4];
        #pragma unroll
        for (int mt = 0; mt < 4; mt++) a[mt] = *(const bf16x8*)(ap[mt] + k);
        #pragma unroll
        for (int nt = 0; nt < 4; nt++) b[nt] = *(const bf16x8*)(bp[nt] + k);
        #pragma unroll
        for (int mt = 0; mt < 4; mt++)
            #pragma unroll
            for (int nt = 0; nt < 4; nt++)
                acc[mt][nt] = __builtin_amdgcn_mfma_f32_16x16x32_bf16(a[mt], b[nt], acc[mt][nt], 0, 0, 0);
    }

    if (wave >= 2){
        #pragma unroll
        for (int mt = 0; mt < 4; mt++)
            #pragma unroll
            for (int nt = 0; nt < 4; nt++)
                #pragma unroll
                for (int r = 0; r < 4; r++)
                    red[wave-2][mt*16 + quad*4 + r][nt*16 + mr] = acc[mt][nt][r];
    }
    __syncthreads();
    if (wave < 2){
        #pragma unroll
        for (int mt = 0; mt < 4; mt++)
            #pragma unroll
            for (int nt = 0; nt < 4; nt++)
                #pragma unroll
                for (int r = 0; r < 4; r++)
                    acc[mt][nt][r] += red[wave][mt*16 + quad*4 + r][nt*16 + mr];
    }
    __syncthreads();
    if (wave == 1){
        #pragma unroll
        for (int mt = 0; mt < 4; mt++)
            #pragma unroll
            for (int nt = 0; nt < 4; nt++)
                #pragma unroll
                for (int r = 0; r < 4; r++)
                    red[0][mt*16 + quad*4 + r][nt*16 + mr] = acc[mt][nt][r];
    }
    __syncthreads();
    if (wave == 0){
        #pragma unroll
        for (int mt = 0; mt < 4; mt++){
            #pragma unroll
            for (int nt = 0; nt < 4; nt++){
                int n = n0 + nt*16 + mr;
                float bv = bias[n];
                #pragma unroll
                for (int r = 0; r < 4; r++){
                    int m = mt*16 + quad*4 + r;
                    float v = acc[mt][nt][r] + red[0][m][nt*16 + mr] + bv;
                    if (n < Hq) h0[(size_t)m*Hq + n] = __float2bfloat16(v);
                    else        c_state[(size_t)m*Hq + (n - Hq)] = v;
                }
            }
        }
    }
}

// ================= att1 GEMM (bf16 A, bf16 out) =================
__global__ __launch_bounds__(256)
void att1_gemm(const bf16_t* __restrict__ A, const bf16_t* __restrict__ W,
               const float* __restrict__ bias, bf16_t* __restrict__ C)
{
    const int lane = threadIdx.x & 63;
    const int wave = threadIdx.x >> 6;
    const int mr = lane & 15;
    const int quad = lane >> 4;
    const int m0 = blockIdx.x * 64;
    const int n0 = (blockIdx.y * 4 + wave) * 64;

    const bf16_t* ap[4];
    const bf16_t* bp[4];
    #pragma unroll
    for (int i = 0; i < 4; i++){
        ap[i] = A + (size_t)(m0 + i*16 + mr)*ENCq + quad*8;
        bp[i] = W + (size_t)(n0 + i*16 + mr)*ENCq + quad*8;
    }
    f32x4 zero = {0.f,0.f,0.f,0.f};
    f32x4 acc[4][4];
    #pragma unroll
    for (int i = 0; i < 4; i++)
        #pragma unroll
        for (int j = 0; j < 4; j++) acc[i][j] = zero;

    for (int k = 0; k < ENCq; k += 32){
        bf16x8 a[4], b[4];
        #pragma unroll
        for (int mt = 0; mt < 4; mt++) a[mt] = *(const bf16x8*)(ap[mt] + k);
        #pragma unroll
        for (int nt = 0; nt < 4; nt++) b[nt] = *(const bf16x8*)(bp[nt] + k);
        #pragma unroll
        for (int mt = 0; mt < 4; mt++)
            #pragma unroll
            for (int nt = 0; nt < 4; nt++)
                acc[mt][nt] = __builtin_amdgcn_mfma_f32_16x16x32_bf16(a[mt], b[nt], acc[mt][nt], 0, 0, 0);
    }
    #pragma unroll
    for (int mt = 0; mt < 4; mt++){
        #pragma unroll
        for (int nt = 0; nt < 4; nt++){
            int n = n0 + nt*16 + mr;
            float bv = bias[n];
            #pragma unroll
            for (int r = 0; r < 4; r++){
                int m = m0 + mt*16 + quad*4 + r;
                C[(size_t)m*Aq + n] = __float2bfloat16(acc[mt][nt][r] + bv);
            }
        }
    }
}

// ================= embedding-part of gates, precomputed for all 29 steps =================
__global__ __launch_bounds__(256)
void embg_gemm(const bf16_t* __restrict__ A, const bf16_t* __restrict__ W,
               float* __restrict__ C)
{
    const int lane = threadIdx.x & 63;
    const int wave = threadIdx.x >> 6;
    const int mr = lane & 15;
    const int quad = lane >> 4;
    const int m0 = blockIdx.x * 64;
    const int n0 = (blockIdx.y * 4 + wave) * 64;

    const bf16_t* ap[4];
    const bf16_t* bp[4];
    #pragma unroll
    for (int i = 0; i < 4; i++){
        ap[i] = A + (size_t)(m0 + i*16 + mr)*512 + quad*8;
        bp[i] = W + (size_t)(n0 + i*16 + mr)*512 + quad*8;
    }
    f32x4 zero = {0.f,0.f,0.f,0.f};
    f32x4 acc[4][4];
    #pragma unroll
    for (int i = 0; i < 4; i++)
        #pragma unroll
        for (int j = 0; j < 4; j++) acc[i][j] = zero;

    #pragma unroll
    for (int kk = 0; kk < 16; kk++){
        bf16x8 a[4], b[4];
        #pragma unroll
        for (int mt = 0; mt < 4; mt++) a[mt] = *(const bf16x8*)(ap[mt] + kk*32);
        #pragma unroll
        for (int nt = 0; nt < 4; nt++) b[nt] = *(const bf16x8*)(bp[nt] + kk*32);
        #pragma unroll
        for (int mt = 0; mt < 4; mt++)
            #pragma unroll
            for (int nt = 0; nt < 4; nt++)
                acc[mt][nt] = __builtin_amdgcn_mfma_f32_16x16x32_bf16(a[mt], b[nt], acc[mt][nt], 0, 0, 0);
    }
    #pragma unroll
    for (int mt = 0; mt < 4; mt++){
        #pragma unroll
        for (int nt = 0; nt < 4; nt++){
            int n = n0 + nt*16 + mr;
            #pragma unroll
            for (int r = 0; r < 4; r++){
                int m = m0 + mt*16 + quad*4 + r;
                C[(size_t)m*2048 + n] = acc[mt][nt][r];
            }
        }
    }
}

// ================= fused per-b attention: att2 GEMV + scores + softmax + gate GEMV + awe + xcat =================
// 64 blocks (one per sorted b) x 512 threads.
__global__ __launch_bounds__(512)
void attn_fused(const bf16_t* __restrict__ att1, const bf16_t* __restrict__ wcat2,
                const float* __restrict__ bias2, const float* __restrict__ faw,
                const float* __restrict__ fab, const int* __restrict__ dec_len,
                const bf16_t* __restrict__ enc_bf, const bf16_t* __restrict__ h_prev,
                float* __restrict__ alphas_out, bf16_t* __restrict__ xcat2, int t)
{
    __shared__ float hls[512];
    __shared__ float a2s[512];
    __shared__ float es[Pq];
    __shared__ float als[Pq];
    __shared__ float red[16];
    const int b = blockIdx.x;
    const int tid = threadIdx.x;
    const int wid = tid >> 6, lane = tid & 63;
    const bf16_t* hp = h_prev + (size_t)b*512;

    // stage h (f32) in LDS
    if (tid < 64){
        bf16x8 hv = ((const bf16x8*)hp)[tid];
        #pragma unroll
        for (int i = 0; i < 8; i++) hls[tid*8 + i] = (float)hv[i];
    }
    __syncthreads();

    // att2[j] = h . dec_att_w[j] + b : one j per thread (rows 0..511 of wcat2)
    {
        const bf16_t* wr = wcat2 + (size_t)tid*512;
        float s = 0.f;
        for (int k = 0; k < 512; k += 8){
            bf16x8 w = *(const bf16x8*)(wr + k);
            float4 h0 = *(const float4*)&hls[k];
            float4 h1 = *(const float4*)&hls[k+4];
            s += h0.x*(float)w[0] + h0.y*(float)w[1] + h0.z*(float)w[2] + h0.w*(float)w[3]
               + h1.x*(float)w[4] + h1.y*(float)w[5] + h1.z*(float)w[6] + h1.w*(float)w[7];
        }
        a2s[tid] = s + bias2[tid];
    }
    __syncthreads();

    // scores e[p] = relu(att1[p] + att2) . faw + fb, 8 waves over p
    {
        float a2r[8], fwr[8];
        const float4* fwp = (const float4*)faw;
        float4 w0 = fwp[lane*2], w1 = fwp[lane*2+1];
        fwr[0]=w0.x; fwr[1]=w0.y; fwr[2]=w0.z; fwr[3]=w0.w;
        fwr[4]=w1.x; fwr[5]=w1.y; fwr[6]=w1.z; fwr[7]=w1.w;
        #pragma unroll
        for (int i = 0; i < 8; i++) a2r[i] = a2s[lane*8 + i];
        float fb = fab[0];
        const bf16_t* a1b = att1 + (size_t)b * Pq * Aq + lane*8;
        for (int p = wid; p < Pq; p += 8){
            bf16x8 rv = *(const bf16x8*)(a1b + (size_t)p * Aq);
            float s = 0.f;
            #pragma unroll
            for (int i = 0; i < 8; i++){
                float v = (float)rv[i] + a2r[i];
                v = v > 0.f ? v : 0.f;
                s += v * fwr[i];
            }
            #pragma unroll
            for (int off = 32; off; off >>= 1) s += __shfl_xor(s, off);
            if (lane == 0) es[p] = s + fb;
        }
    }
    __syncthreads();

    // softmax over 196
    {
        float v = (tid < Pq) ? es[tid] : -3.4e38f;
        float m = v;
        #pragma unroll
        for (int off = 32; off; off >>= 1) m = fmaxf(m, __shfl_xor(m, off));
        if (lane == 0) red[wid] = m;
        __syncthreads();
        float bm = red[0];
        #pragma unroll
        for (int w = 1; w < 8; w++) bm = fmaxf(bm, red[w]);
        float ex = (tid < Pq) ? expf(v - bm) : 0.f;
        float s = ex;
        #pragma unroll
        for (int off = 32; off; off >>= 1) s += __shfl_xor(s, off);
        if (lane == 0) red[8 + wid] = s;
        __syncthreads();
        float bs = red[8];
        #pragma unroll
        for (int w = 1; w < 8; w++) bs += red[8 + w];
        if (tid < Pq){
            float al = ex / bs;
            als[tid] = al;
            float mask = (t < dec_len[b]) ? 1.f : 0.f;
            alphas_out[((size_t)b*Tq + t)*Pq + tid] = al * mask;
        }
    }
    __syncthreads();

    // gate GEMV (4 rows of f_beta part per thread) + awe (4 d per thread) + xcat write
    {
        const int d0 = tid * 4;
        const bf16_t* wr = wcat2 + (size_t)(512 + d0)*512;
        f32x4 gs = {0.f,0.f,0.f,0.f};
        for (int k = 0; k < 512; k += 8){
            float4 h0 = *(const float4*)&hls[k];
            float4 h1 = *(const float4*)&hls[k+4];
            #pragma unroll
            for (int r = 0; r < 4; r++){
                bf16x8 w = *(const bf16x8*)(wr + (size_t)r*512 + k);
                gs[r] += h0.x*(float)w[0] + h0.y*(float)w[1] + h0.z*(float)w[2] + h0.w*(float)w[3]
                       + h1.x*(float)w[4] + h1.y*(float)w[5] + h1.z*(float)w[6] + h1.w*(float)w[7];
            }
        }
        const bf16_t* eb = enc_bf + (size_t)b * Pq * ENCq + d0;
        f32x4 sa = {0.f,0.f,0.f,0.f};
        for (int p = 0; p < Pq; p++){
            bf16x4 ev = *(const bf16x4*)(eb + (size_t)p*ENCq);
            float al = als[p];
            sa[0] += al*(float)ev[0];
            sa[1] += al*(float)ev[1];
            sa[2] += al*(float)ev[2];
            sa[3] += al*(float)ev[3];
        }
        bf16_t* xo = xcat2 + (size_t)b*2560 + d0;
        #pragma unroll
        for (int r = 0; r < 4; r++){
            float g = sigmoidf_(gs[r] + bias2[512 + d0 + r]);
            xo[r] = __float2bfloat16(g * sa[r]);
        }
    }
    // h tail of xcat
    xcat2[(size_t)b*2560 + 2048 + tid] = hp[tid];
}

// ================= gates GEMM (K=2560, 16-wide n-tiles, 4-wave K-split) + LSTM =================
__global__ __launch_bounds__(256)
void gates_lstm2(const bf16_t* __restrict__ A, const bf16_t* __restrict__ W,
                 const float* __restrict__ bias, const float* __restrict__ gE,
                 float* __restrict__ c_state, bf16_t* __restrict__ h_next)
{
    __shared__ float red4[2][64][17];
    const int lane = threadIdx.x & 63;
    const int wid  = threadIdx.x >> 6;
    const int mr = lane & 15;
    const int quad = lane >> 4;
    const int n0 = blockIdx.x * 16;
    const int kbeg = wid * 640;

    const bf16_t* ap[4];
    #pragma unroll
    for (int i = 0; i < 4; i++) ap[i] = A + (size_t)(i*16 + mr)*2560 + quad*8;
    const bf16_t* bp = W + (size_t)(n0 + mr)*2560 + quad*8;

    f32x4 zero = {0.f,0.f,0.f,0.f};
    f32x4 acc[4] = {zero, zero, zero, zero};
    for (int k = kbeg; k < kbeg + 640; k += 32){
        bf16x8 bfr = *(const bf16x8*)(bp + k);
        bf16x8 a[4];
        #pragma unroll
        for (int mt = 0; mt < 4; mt++) a[mt] = *(const bf16x8*)(ap[mt] + k);
        #pragma unroll
        for (int mt = 0; mt < 4; mt++)
            acc[mt] = __builtin_amdgcn_mfma_f32_16x16x32_bf16(a[mt], bfr, acc[mt], 0, 0, 0);
    }
    if (wid >= 2){
        #pragma unroll
        for (int mt = 0; mt < 4; mt++)
            #pragma unroll
            for (int r = 0; r < 4; r++)
                red4[wid-2][mt*16 + quad*4 + r][mr] = acc[mt][r];
    }
    __syncthreads();
    if (wid < 2){
        #pragma unroll
        for (int mt = 0; mt < 4; mt++)
            #pragma unroll
            for (int r = 0; r < 4; r++)
                acc[mt][r] += red4[wid][mt*16 + quad*4 + r][mr];
    }
    __syncthreads();
    if (wid == 1){
        #pragma unroll
        for (int mt = 0; mt < 4; mt++)
            #pragma unroll
            for (int r = 0; r < 4; r++)
                red4[0][mt*16 + quad*4 + r][mr] = acc[mt][r];
    }
    __syncthreads();
    if (wid == 0){
        float bv = bias[n0 + mr];
        #pragma unroll
        for (int mt = 0; mt < 4; mt++){
            #pragma unroll
            for (int r = 0; r < 4; r++){
                int m = mt*16 + quad*4 + r;
                float ge = gE[(size_t)m*2048 + n0 + mr];
                red4[0][m][mr] = acc[mt][r] + red4[0][m][mr] + bv + ge;  // same-lane RW: safe
            }
        }
    }
    __syncthreads();
    {
        int m = threadIdx.x & 63, jl = threadIdx.x >> 6;
        int j = blockIdx.x*4 + jl;
        float gi = sigmoidf_(red4[0][m][4*jl + 0]);
        float gf = sigmoidf_(red4[0][m][4*jl + 1]);
        float gv = tanhf(red4[0][m][4*jl + 2]);
        float go = sigmoidf_(red4[0][m][4*jl + 3]);
        float cc = c_state[m*512 + j];
        float cn = gf*cc + gi*gv;
        float hn = go * tanhf(cn);
        c_state[m*512 + j] = cn;
        h_next[m*512 + j] = __float2bfloat16(hn);
    }
}

// ================= batched preds GEMM: W tile LDS-resident, waves split m =================
// grid 469 blocks (n-tile 64); block stages W[n0:n0+64][512] in LDS once; wave w does m-tiles w,w+4,...
__global__ __launch_bounds__(256)
void preds_batched2(const bf16_t* __restrict__ Ah, const bf16_t* __restrict__ W,
                    const float* __restrict__ bias, float* __restrict__ C,
                    const int* __restrict__ dec_len)
{
    __shared__ __bf16 Ws[64][520];
    const int tid = threadIdx.x;
    const int lane = tid & 63;
    const int wave = tid >> 6;
    const int mr = lane & 15;
    const int quad = lane >> 4;
    const int n0 = blockIdx.x * 64;

    {
        int r = tid >> 2;
        int c0 = (tid & 3) * 128;
        int row = n0 + r; if (row > Vq-1) row = Vq-1;
        const bf16_t* src = W + (size_t)row*512 + c0;
        #pragma unroll
        for (int i = 0; i < 16; i++)
            *(bf16x8*)&Ws[r][c0 + i*8] = *(const bf16x8*)(src + i*8);
    }
    __syncthreads();

    for (int mi = wave; mi < 29; mi += 4){
        const int m0 = mi * 64;
        const bf16_t* ap[4];
        #pragma unroll
        for (int i = 0; i < 4; i++)
            ap[i] = Ah + (size_t)(m0 + i*16 + mr)*512 + quad*8;

        f32x4 zero = {0.f,0.f,0.f,0.f};
        f32x4 acc[4][4];
        #pragma unroll
        for (int i = 0; i < 4; i++)
            #pragma unroll
            for (int j = 0; j < 4; j++) acc[i][j] = zero;

        #pragma unroll
        for (int kk = 0; kk < 16; kk++){
            bf16x8 a[4], bw[4];
            #pragma unroll
            for (int mt = 0; mt < 4; mt++) a[mt] = *(const bf16x8*)(ap[mt] + kk*32);
            #pragma unroll
            for (int nt = 0; nt < 4; nt++) bw[nt] = *(const bf16x8*)&Ws[nt*16 + mr][kk*32 + quad*8];
            #pragma unroll
            for (int mt = 0; mt < 4; mt++)
                #pragma unroll
                for (int nt = 0; nt < 4; nt++)
                    acc[mt][nt] = __builtin_amdgcn_mfma_f32_16x16x32_bf16(bw[nt], a[mt], acc[mt][nt], 0, 0, 0);
        }

        // swapped-operand D layout: lane col (mr) = m, quad*4+r = n offset
        #pragma unroll
        for (int mt = 0; mt < 4; mt++){
            int m = m0 + mt*16 + mr;
            int tt = m >> 6, bb = m & 63;
            bool msk = (tt >= dec_len[bb]);
            float* crow = C + (size_t)bb*(Tq*Vq) + (size_t)tt*Vq;
            #pragma unroll
            for (int nt = 0; nt < 4; nt++){
                int n = n0 + nt*16 + quad*4;
                if (n < Vq){
                    float4 bv = *(const float4*)(bias + n);
                    f32x4 v = acc[mt][nt];
                    float4 o;
                    o.x = msk ? 0.f : (v[0] + bv.x);
                    o.y = msk ? 0.f : (v[1] + bv.y);
                    o.z = msk ? 0.f : (v[2] + bv.z);
                    o.w = msk ? 0.f : (v[3] + bv.w);
                    *(float4*)(crow + n) = o;
                }
            }
        }
    }
}

extern "C" void kernel_launch(void* const* d_in, const int* in_sizes, int n_in,
                              void* d_out, int out_size, void* d_ws, size_t ws_size,
                              hipStream_t stream)
{
    const float* encoder_out = (const float*)d_in[0];
    const float* enc_att_w   = (const float*)d_in[1];
    const float* enc_att_b   = (const float*)d_in[2];
    const float* dec_att_w   = (const float*)d_in[3];
    const float* dec_att_b   = (const float*)d_in[4];
    const float* full_att_w  = (const float*)d_in[5];
    const float* full_att_b  = (const float*)d_in[6];
    const float* embed       = (const float*)d_in[7];
    const float* W_ih        = (const float*)d_in[8];
    const float* W_hh        = (const float*)d_in[9];
    const float* b_ih        = (const float*)d_in[10];
    const float* b_hh        = (const float*)d_in[11];
    const float* init_h_w    = (const float*)d_in[12];
    const float* init_h_b    = (const float*)d_in[13];
    const float* init_c_w    = (const float*)d_in[14];
    const float* init_c_b    = (const float*)d_in[15];
    const float* f_beta_w    = (const float*)d_in[16];
    const float* f_beta_b    = (const float*)d_in[17];
    const float* fc_w        = (const float*)d_in[18];
    const float* fc_b        = (const float*)d_in[19];
    const int*   enc_caps    = (const int*)d_in[20];
    const int*   cap_len     = (const int*)d_in[21];

    float* out_preds   = (float*)d_out;
    float* out_caps    = out_preds + (size_t)Bq*Tq*Vq;
    float* out_declen  = out_caps + Bq*Lq;
    float* out_alphas  = out_declen + Bq;
    float* out_sortind = out_alphas + (size_t)Bq*Tq*Pq;

    char* cur = (char*)d_ws;
    auto alloc = [&](size_t bytes) -> char* {
        char* p = cur;
        cur += (bytes + 255) & ~(size_t)255;
        return p;
    };
    bf16_t* enc_bf    = (bf16_t*)alloc((size_t)12544*2048*2);
    bf16_t* att1_bf   = (bf16_t*)alloc((size_t)12544*512*2);
    bf16_t* fcw_bf    = (bf16_t*)alloc((size_t)30000*512*2);
    bf16_t* wcatg_bf  = (bf16_t*)alloc((size_t)2048*2560*2);
    bf16_t* wembg_bf  = (bf16_t*)alloc((size_t)2048*512*2);
    bf16_t* embA_bf   = (bf16_t*)alloc((size_t)1856*512*2);
    float*  gatesE    = (float*)alloc((size_t)1856*2048*4);
    bf16_t* whc_bf    = (bf16_t*)alloc((size_t)1024*2048*2);
    bf16_t* wcat2_bf  = (bf16_t*)alloc((size_t)2560*512*2);
    bf16_t* encattw_bf= (bf16_t*)alloc((size_t)512*2048*2);
    bf16_t* meanenc_bf= (bf16_t*)alloc((size_t)64*2048*2);
    bf16_t* h_hist    = (bf16_t*)alloc((size_t)30*64*512*2);   // slot 0 = h0, slot t+1 = h after step t
    bf16_t* xcat2_bf  = (bf16_t*)alloc((size_t)64*2560*2);
    float* c_state   = (float*)alloc((size_t)64*512*4);
    float* bias_hc   = (float*)alloc(1024*4);
    float* bias2     = (float*)alloc(2560*4);
    float* bias_g    = (float*)alloc(2048*4);
    int* caps_sorted = (int*)alloc(Bq*Lq*4);
    int* sort_ind_i  = (int*)alloc(64*4);
    int* dec_len_i   = (int*)alloc(64*4);

    // ---- setup ----
    sort_kernel<<<1, 64, 0, stream>>>(cap_len, enc_caps, sort_ind_i, dec_len_i,
                                      caps_sorted, out_caps, out_declen, out_sortind);

    cvt_bf16<<<(1048576+255)/256, 256, 0, stream>>>(encattw_bf, enc_att_w, 1048576);
    cvt_bf16<<<(15360000+255)/256, 256, 0, stream>>>(fcw_bf, fc_w, 15360000);
    pack_rowcat_bf16<<<(2097152+255)/256, 256, 0, stream>>>(whc_bf, init_h_w, 1048576, init_c_w, 1048576);
    pack_rowcat_bf16<<<(1310720+255)/256, 256, 0, stream>>>(wcat2_bf, dec_att_w, 262144, f_beta_w, 1048576);
    pack_wcatg2<<<(2048*2560+255)/256, 256, 0, stream>>>(wcatg_bf, W_ih, W_hh);
    pack_wembg<<<(2048*512+255)/256, 256, 0, stream>>>(wembg_bf, W_ih);
    pack_rowcat_f32<<<(1024+255)/256, 256, 0, stream>>>(bias_hc, init_h_b, 512, init_c_b, 512);
    pack_rowcat_f32<<<(2560+255)/256, 256, 0, stream>>>(bias2, dec_att_b, 512, f_beta_b, 2048);
    biasg_perm_kernel<<<8, 256, 0, stream>>>(bias_g, b_ih, b_hh);

    // emb gather (needs sort) + precomputed emb-part of gates for all 29 steps
    gather_emb<<<1856, 256, 0, stream>>>(embed, caps_sorted, embA_bf);
    embg_gemm<<<dim3(29,8), 256, 0, stream>>>(embA_bf, wembg_bf, gatesE);

    gather_cvt_mean<<<dim3(64,8), 256, 0, stream>>>(encoder_out, sort_ind_i, enc_bf, meanenc_bf);

    // h0/c0: M=64, N=1024, K=2048
    hc0_ksplit<<<16, 256, 0, stream>>>(meanenc_bf, whc_bf, bias_hc, h_hist, c_state);

    // att1: M=12544 (sorted), N=512, K=2048
    att1_gemm<<<dim3(196,2), 256, 0, stream>>>(enc_bf, encattw_bf, enc_att_b, att1_bf);

    for (int t = 0; t < Tq; t++){
        const bf16_t* h_prev = h_hist + (size_t)t*Bq*Hq;
        bf16_t* h_next = h_hist + (size_t)(t+1)*Bq*Hq;

        attn_fused<<<64, 512, 0, stream>>>(att1_bf, wcat2_bf, bias2, full_att_w, full_att_b,
                                           dec_len_i, enc_bf, h_prev, out_alphas, xcat2_bf, t);

        gates_lstm2<<<128, 256, 0, stream>>>(xcat2_bf, wcatg_bf, bias_g,
                                             gatesE + (size_t)t*64*2048, c_state, h_next);
    }

    // batched preds over all 29 steps: M=1856, N=30000, K=512
    preds_batched2<<<469, 256, 0, stream>>>(h_hist + (size_t)Bq*Hq, fcw_bf, fc_b,
                                            out_preds, dec_len_i);
}

// Round 4
// 2564.626 us; speedup vs baseline: 1.7893x; 1.7893x over previous
//
#include <hip/hip_runtime.h>
#include <hip/hip_bf16.h>
#include <cstdint>

#define Bq 64
#define Pq 196
#define ENCq 2048
#define Aq 512
#define Hq 512
#define Vq 30000
#define Lq 30
#define Tq 29

typedef __bf16 bf16x8 __attribute__((ext_vector_type(8)));
typedef float f32x4 __attribute__((ext_vector_type(4)));
typedef __hip_bfloat16 bf16_t;

__device__ __forceinline__ float sigmoidf_(float x){ return 1.0f/(1.0f+expf(-x)); }

// ---------------- sort (stable descending argsort of lengths) ----------------
__global__ void sort_kernel(const int* __restrict__ cap_len, const int* __restrict__ caps,
                            int* __restrict__ sort_ind_i, int* __restrict__ dec_len_i,
                            int* __restrict__ caps_sorted,
                            float* __restrict__ out_caps, float* __restrict__ out_declen,
                            float* __restrict__ out_sortind)
{
    __shared__ int len[Bq];
    __shared__ int sidx[Bq];
    int i = threadIdx.x;
    len[i] = cap_len[i];
    __syncthreads();
    int li = len[i];
    int rank = 0;
    for (int j = 0; j < Bq; j++){
        int lj = len[j];
        rank += (lj > li) || (lj == li && j < i);
    }
    sidx[rank] = i;
    __syncthreads();
    int src = sidx[i];
    sort_ind_i[i] = src;
    int dl = len[src] - 1;
    dec_len_i[i] = dl;
    out_declen[i] = (float)dl;
    out_sortind[i] = (float)src;
    for (int tt = 0; tt < Lq; tt++){
        int cv = caps[src*Lq + tt];
        caps_sorted[i*Lq + tt] = cv;
        out_caps[i*Lq + tt] = (float)cv;
    }
}

// ---------------- pack / convert helpers ----------------
__global__ void cvt_bf16(bf16_t* __restrict__ dst, const float* __restrict__ src, int n)
{
    int i = blockIdx.x*256 + threadIdx.x;
    if (i < n) dst[i] = __float2bfloat16(src[i]);
}

__global__ void pack_rowcat_bf16(bf16_t* __restrict__ dst, const float* __restrict__ a, int na,
                                 const float* __restrict__ b, int nb)
{
    int i = blockIdx.x*256 + threadIdx.x;
    if (i < na) dst[i] = __float2bfloat16(a[i]);
    else if (i < na + nb) dst[i] = __float2bfloat16(b[i - na]);
}

__global__ void pack_rowcat_f32(float* __restrict__ dst, const float* __restrict__ a, int na,
                                const float* __restrict__ b, int nb)
{
    int i = blockIdx.x*256 + threadIdx.x;
    if (i < na) dst[i] = a[i];
    else if (i < na + nb) dst[i] = b[i - na];
}

// gates weight, permuted rows (rp = 4j+g -> r = g*512+j), cols = [W_ih awe-part (2048) | W_hh (512)]
__global__ void pack_wcatg2(bf16_t* __restrict__ dst, const float* __restrict__ wih,
                            const float* __restrict__ whh)
{
    int i = blockIdx.x*256 + threadIdx.x;
    if (i >= 2048*2560) return;
    int rp = i / 2560, c = i % 2560;
    int g = rp & 3, j = rp >> 2;
    int r = g*512 + j;
    float v = (c < 2048) ? wih[(size_t)r*2560 + 512 + c] : whh[(size_t)r*512 + (c - 2048)];
    dst[i] = __float2bfloat16(v);
}

// emb-part of W_ih, permuted rows, K=512
__global__ void pack_wembg(bf16_t* __restrict__ dst, const float* __restrict__ wih)
{
    int i = blockIdx.x*256 + threadIdx.x;
    if (i >= 2048*512) return;
    int rp = i >> 9, c = i & 511;
    int g = rp & 3, j = rp >> 2;
    int r = g*512 + j;
    dst[i] = __float2bfloat16(wih[(size_t)r*2560 + c]);
}

__global__ void biasg_perm_kernel(float* __restrict__ dst, const float* __restrict__ bi,
                                  const float* __restrict__ bh)
{
    int i = blockIdx.x*256 + threadIdx.x;
    if (i >= 2048) return;
    int g = i & 3, j = i >> 2;
    int r = g*512 + j;
    dst[i] = bi[r] + bh[r];
}

// embA row m = t*64 + b  :=  bf16(embed[caps_sorted[b][t]])
__global__ void gather_emb(const float* __restrict__ embed, const int* __restrict__ caps_sorted,
                           bf16_t* __restrict__ embA)
{
    int m = blockIdx.x;            // 0..1855
    int t = m >> 6, b = m & 63;
    int cap = caps_sorted[b*Lq + t];
    const float* er = embed + (size_t)cap*512;
    bf16_t* dr = embA + (size_t)m*512;
    for (int j = threadIdx.x; j < 512; j += 256) dr[j] = __float2bfloat16(er[j]);
}

// ---------------- gather encoder into sorted order, convert to bf16, compute mean ----------------
__global__ __launch_bounds__(256)
void gather_cvt_mean(const float* __restrict__ enc, const int* __restrict__ sort_ind,
                     bf16_t* __restrict__ enc_bf, bf16_t* __restrict__ mean_bf)
{
    int b = blockIdx.x;
    int d = blockIdx.y*256 + threadIdx.x;
    int src = sort_ind[b];
    const float* col = enc + (size_t)src * Pq * ENCq + d;
    bf16_t* dst = enc_bf + (size_t)b * Pq * ENCq + d;
    float s = 0.f;
    for (int p = 0; p < Pq; p++){
        float v = col[(size_t)p*ENCq];
        s += v;
        dst[(size_t)p*ENCq] = __float2bfloat16(v);
    }
    mean_bf[(size_t)b*ENCq + d] = __float2bfloat16(s * (1.0f/196.0f));
}

// ================= h0/c0 GEMM: waves split K, LDS reduce =================
__global__ __launch_bounds__(256)
void hc0_ksplit(const bf16_t* __restrict__ A, const bf16_t* __restrict__ W,
                const float* __restrict__ bias,
                bf16_t* __restrict__ h0, float* __restrict__ c_state)
{
    __shared__ float red[2][64][64];
    const int lane = threadIdx.x & 63;
    const int wave = threadIdx.x >> 6;
    const int mr = lane & 15;
    const int quad = lane >> 4;
    const int n0 = blockIdx.x * 64;
    const int kw = 2048 >> 2;
    const int kbeg = wave * kw;

    const bf16_t* ap[4];
    const bf16_t* bp[4];
    #pragma unroll
    for (int i = 0; i < 4; i++){
        ap[i] = A + (size_t)(i*16 + mr)*2048 + quad*8;
        bp[i] = W + (size_t)(n0 + i*16 + mr)*2048 + quad*8;
    }
    f32x4 zero = {0.f,0.f,0.f,0.f};
    f32x4 acc[4][4];
    #pragma unroll
    for (int i = 0; i < 4; i++)
        #pragma unroll
        for (int j = 0; j < 4; j++) acc[i][j] = zero;

    for (int k = kbeg; k < kbeg + kw; k += 32){
        bf16x8 a[4], b[4];
        #pragma unroll
        for (int mt = 0; mt < 4; mt++) a[mt] = *(const bf16x8*)(ap[mt] + k);
        #pragma unroll
        for (int nt = 0; nt < 4; nt++) b[nt] = *(const bf16x8*)(bp[nt] + k);
        #pragma unroll
        for (int mt = 0; mt < 4; mt++)
            #pragma unroll
            for (int nt = 0; nt < 4; nt++)
                acc[mt][nt] = __builtin_amdgcn_mfma_f32_16x16x32_bf16(a[mt], b[nt], acc[mt][nt], 0, 0, 0);
    }

    if (wave >= 2){
        #pragma unroll
        for (int mt = 0; mt < 4; mt++)
            #pragma unroll
            for (int nt = 0; nt < 4; nt++)
                #pragma unroll
                for (int r = 0; r < 4; r++)
                    red[wave-2][mt*16 + quad*4 + r][nt*16 + mr] = acc[mt][nt][r];
    }
    __syncthreads();
    if (wave < 2){
        #pragma unroll
        for (int mt = 0; mt < 4; mt++)
            #pragma unroll
            for (int nt = 0; nt < 4; nt++)
                #pragma unroll
                for (int r = 0; r < 4; r++)
                    acc[mt][nt][r] += red[wave][mt*16 + quad*4 + r][nt*16 + mr];
    }
    __syncthreads();
    if (wave == 1){
        #pragma unroll
        for (int mt = 0; mt < 4; mt++)
            #pragma unroll
            for (int nt = 0; nt < 4; nt++)
                #pragma unroll
                for (int r = 0; r < 4; r++)
                    red[0][mt*16 + quad*4 + r][nt*16 + mr] = acc[mt][nt][r];
    }
    __syncthreads();
    if (wave == 0){
        #pragma unroll
        for (int mt = 0; mt < 4; mt++){
            #pragma unroll
            for (int nt = 0; nt < 4; nt++){
                int n = n0 + nt*16 + mr;
                float bv = bias[n];
                #pragma unroll
                for (int r = 0; r < 4; r++){
                    int m = mt*16 + quad*4 + r;
                    float v = acc[mt][nt][r] + red[0][m][nt*16 + mr] + bv;
                    if (n < Hq) h0[(size_t)m*Hq + n] = __float2bfloat16(v);
                    else        c_state[(size_t)m*Hq + (n - Hq)] = v;
                }
            }
        }
    }
}

// ================= att1 GEMM (bf16 A, bf16 out) =================
__global__ __launch_bounds__(256)
void att1_gemm(const bf16_t* __restrict__ A, const bf16_t* __restrict__ W,
               const float* __restrict__ bias, bf16_t* __restrict__ C)
{
    const int lane = threadIdx.x & 63;
    const int wave = threadIdx.x >> 6;
    const int mr = lane & 15;
    const int quad = lane >> 4;
    const int m0 = blockIdx.x * 64;
    const int n0 = (blockIdx.y * 4 + wave) * 64;

    const bf16_t* ap[4];
    const bf16_t* bp[4];
    #pragma unroll
    for (int i = 0; i < 4; i++){
        ap[i] = A + (size_t)(m0 + i*16 + mr)*ENCq + quad*8;
        bp[i] = W + (size_t)(n0 + i*16 + mr)*ENCq + quad*8;
    }
    f32x4 zero = {0.f,0.f,0.f,0.f};
    f32x4 acc[4][4];
    #pragma unroll
    for (int i = 0; i < 4; i++)
        #pragma unroll
        for (int j = 0; j < 4; j++) acc[i][j] = zero;

    for (int k = 0; k < ENCq; k += 32){
        bf16x8 a[4], b[4];
        #pragma unroll
        for (int mt = 0; mt < 4; mt++) a[mt] = *(const bf16x8*)(ap[mt] + k);
        #pragma unroll
        for (int nt = 0; nt < 4; nt++) b[nt] = *(const bf16x8*)(bp[nt] + k);
        #pragma unroll
        for (int mt = 0; mt < 4; mt++)
            #pragma unroll
            for (int nt = 0; nt < 4; nt++)
                acc[mt][nt] = __builtin_amdgcn_mfma_f32_16x16x32_bf16(a[mt], b[nt], acc[mt][nt], 0, 0, 0);
    }
    #pragma unroll
    for (int mt = 0; mt < 4; mt++){
        #pragma unroll
        for (int nt = 0; nt < 4; nt++){
            int n = n0 + nt*16 + mr;
            float bv = bias[n];
            #pragma unroll
            for (int r = 0; r < 4; r++){
                int m = m0 + mt*16 + quad*4 + r;
                C[(size_t)m*Aq + n] = __float2bfloat16(acc[mt][nt][r] + bv);
            }
        }
    }
}

// ================= embedding-part of gates, precomputed for all 29 steps =================
__global__ __launch_bounds__(256)
void embg_gemm(const bf16_t* __restrict__ A, const bf16_t* __restrict__ W,
               float* __restrict__ C)
{
    const int lane = threadIdx.x & 63;
    const int wave = threadIdx.x >> 6;
    const int mr = lane & 15;
    const int quad = lane >> 4;
    const int m0 = blockIdx.x * 64;
    const int n0 = (blockIdx.y * 4 + wave) * 64;

    const bf16_t* ap[4];
    const bf16_t* bp[4];
    #pragma unroll
    for (int i = 0; i < 4; i++){
        ap[i] = A + (size_t)(m0 + i*16 + mr)*512 + quad*8;
        bp[i] = W + (size_t)(n0 + i*16 + mr)*512 + quad*8;
    }
    f32x4 zero = {0.f,0.f,0.f,0.f};
    f32x4 acc[4][4];
    #pragma unroll
    for (int i = 0; i < 4; i++)
        #pragma unroll
        for (int j = 0; j < 4; j++) acc[i][j] = zero;

    #pragma unroll
    for (int kk = 0; kk < 16; kk++){
        bf16x8 a[4], b[4];
        #pragma unroll
        for (int mt = 0; mt < 4; mt++) a[mt] = *(const bf16x8*)(ap[mt] + kk*32);
        #pragma unroll
        for (int nt = 0; nt < 4; nt++) b[nt] = *(const bf16x8*)(bp[nt] + kk*32);
        #pragma unroll
        for (int mt = 0; mt < 4; mt++)
            #pragma unroll
            for (int nt = 0; nt < 4; nt++)
                acc[mt][nt] = __builtin_amdgcn_mfma_f32_16x16x32_bf16(a[mt], b[nt], acc[mt][nt], 0, 0, 0);
    }
    #pragma unroll
    for (int mt = 0; mt < 4; mt++){
        #pragma unroll
        for (int nt = 0; nt < 4; nt++){
            int n = n0 + nt*16 + mr;
            #pragma unroll
            for (int r = 0; r < 4; r++){
                int m = m0 + mt*16 + quad*4 + r;
                C[(size_t)m*2048 + n] = acc[mt][nt][r];
            }
        }
    }
}

// ================= att2|gate GEMM: LDS-staged h, single K pass =================
__global__ __launch_bounds__(256)
void attg_gemm(const bf16_t* __restrict__ h, const bf16_t* __restrict__ W,
               const float* __restrict__ bias, float* __restrict__ C)
{
    __shared__ __bf16 hs[64][520];
    {
        int r = threadIdx.x >> 2;
        int c0 = (threadIdx.x & 3) * 128;
        const bf16_t* src = h + (size_t)r*512 + c0;
        #pragma unroll
        for (int i = 0; i < 16; i++)
            *(bf16x8*)&hs[r][c0 + i*8] = *(const bf16x8*)(src + i*8);
    }
    __syncthreads();

    const int lane = threadIdx.x & 63;
    const int wave = threadIdx.x >> 6;
    const int mr = lane & 15;
    const int quad = lane >> 4;
    const int n0 = (blockIdx.x * 4 + wave) * 16;

    const bf16_t* bp = W + (size_t)(n0 + mr)*512 + quad*8;
    f32x4 zero = {0.f,0.f,0.f,0.f};
    f32x4 acc[4] = {zero, zero, zero, zero};

    #pragma unroll
    for (int kk = 0; kk < 16; kk++){
        bf16x8 b = *(const bf16x8*)(bp + kk*32);
        bf16x8 a[4];
        #pragma unroll
        for (int mt = 0; mt < 4; mt++)
            a[mt] = *(const bf16x8*)&hs[mt*16 + mr][kk*32 + quad*8];
        #pragma unroll
        for (int mt = 0; mt < 4; mt++)
            acc[mt] = __builtin_amdgcn_mfma_f32_16x16x32_bf16(a[mt], b, acc[mt], 0, 0, 0);
    }

    float bv = bias[n0 + mr];
    #pragma unroll
    for (int mt = 0; mt < 4; mt++){
        #pragma unroll
        for (int r = 0; r < 4; r++){
            int m = mt*16 + quad*4 + r;
            C[(size_t)m*2560 + n0 + mr] = acc[mt][r] + bv;
        }
    }
}

// ================= fused scores+softmax+awe: grid (64 b, 4 y) x 512 thr =================
// Each block recomputes scores/softmax for its b (deterministic, identical across y),
// then computes awe slice d = y*512 + tid and writes gated awe into xcat2.
__global__ __launch_bounds__(512)
void awe_attn(const bf16_t* __restrict__ att1, const float* __restrict__ att2gate,
              const float* __restrict__ faw, const float* __restrict__ fab,
              const int* __restrict__ dec_len, const bf16_t* __restrict__ enc_bf,
              const bf16_t* __restrict__ h_prev, float* __restrict__ alphas_out,
              bf16_t* __restrict__ xcat2, int t)
{
    __shared__ float es[Pq];
    __shared__ float als[Pq];
    __shared__ float red[16];
    const int b = blockIdx.x, y = blockIdx.y;
    const int tid = threadIdx.x;
    const int wid = tid >> 6, lane = tid & 63;

    // scores e[p] = relu(att1[p] + att2) . faw + fb, 8 waves over p
    {
        float a2r[8], fwr[8];
        const float4* a2p = (const float4*)(att2gate + (size_t)b*2560);
        const float4* fwp = (const float4*)faw;
        float4 u0 = a2p[lane*2], u1 = a2p[lane*2+1];
        float4 w0 = fwp[lane*2], w1 = fwp[lane*2+1];
        a2r[0]=u0.x; a2r[1]=u0.y; a2r[2]=u0.z; a2r[3]=u0.w;
        a2r[4]=u1.x; a2r[5]=u1.y; a2r[6]=u1.z; a2r[7]=u1.w;
        fwr[0]=w0.x; fwr[1]=w0.y; fwr[2]=w0.z; fwr[3]=w0.w;
        fwr[4]=w1.x; fwr[5]=w1.y; fwr[6]=w1.z; fwr[7]=w1.w;
        float fb = fab[0];
        const bf16_t* a1b = att1 + (size_t)b * Pq * Aq + lane*8;
        for (int p = wid; p < Pq; p += 8){
            bf16x8 rv = *(const bf16x8*)(a1b + (size_t)p * Aq);
            float s = 0.f;
            #pragma unroll
            for (int i = 0; i < 8; i++){
                float v = (float)rv[i] + a2r[i];
                v = v > 0.f ? v : 0.f;
                s += v * fwr[i];
            }
            #pragma unroll
            for (int off = 32; off; off >>= 1) s += __shfl_xor(s, off);
            if (lane == 0) es[p] = s + fb;
        }
    }
    __syncthreads();

    // softmax over 196 (8 waves participate; tid>=196 contribute identity)
    {
        float v = (tid < Pq) ? es[tid] : -3.4e38f;
        float m = v;
        #pragma unroll
        for (int off = 32; off; off >>= 1) m = fmaxf(m, __shfl_xor(m, off));
        if (lane == 0) red[wid] = m;
        __syncthreads();
        float bm = red[0];
        #pragma unroll
        for (int w = 1; w < 8; w++) bm = fmaxf(bm, red[w]);
        float ex = (tid < Pq) ? expf(v - bm) : 0.f;
        float s = ex;
        #pragma unroll
        for (int off = 32; off; off >>= 1) s += __shfl_xor(s, off);
        if (lane == 0) red[8 + wid] = s;
        __syncthreads();
        float bs = red[8];
        #pragma unroll
        for (int w = 1; w < 8; w++) bs += red[8 + w];
        if (tid < Pq){
            float al = ex / bs;
            als[tid] = al;
            if (y == 0){
                float mask = (t < dec_len[b]) ? 1.f : 0.f;
                alphas_out[((size_t)b*Tq + t)*Pq + tid] = al * mask;
            }
        }
    }
    __syncthreads();

    // awe for d = y*512 + tid; gate from att2gate; write gated awe
    {
        int d = y*512 + tid;
        const bf16_t* ebase = enc_bf + (size_t)b * Pq * ENCq + d;
        float s = 0.f;
        #pragma unroll 4
        for (int p = 0; p < Pq; p++) s += als[p] * (float)ebase[(size_t)p*ENCq];
        float g = sigmoidf_(att2gate[(size_t)b*2560 + 512 + d]);
        xcat2[(size_t)b*2560 + d] = __float2bfloat16(g * s);
    }
    // h tail of xcat (512 values, once per b)
    if (y == 0)
        xcat2[(size_t)b*2560 + 2048 + tid] = h_prev[(size_t)b*512 + tid];
}

// ================= gates GEMM (K=2560, 16-wide n-tiles, 4-wave K-split) + LSTM =================
__global__ __launch_bounds__(256)
void gates_lstm2(const bf16_t* __restrict__ A, const bf16_t* __restrict__ W,
                 const float* __restrict__ bias, const float* __restrict__ gE,
                 float* __restrict__ c_state, bf16_t* __restrict__ h_next)
{
    __shared__ float red4[2][64][17];
    const int lane = threadIdx.x & 63;
    const int wid  = threadIdx.x >> 6;
    const int mr = lane & 15;
    const int quad = lane >> 4;
    const int n0 = blockIdx.x * 16;
    const int kbeg = wid * 640;

    const bf16_t* ap[4];
    #pragma unroll
    for (int i = 0; i < 4; i++) ap[i] = A + (size_t)(i*16 + mr)*2560 + quad*8;
    const bf16_t* bp = W + (size_t)(n0 + mr)*2560 + quad*8;

    f32x4 zero = {0.f,0.f,0.f,0.f};
    f32x4 acc[4] = {zero, zero, zero, zero};
    for (int k = kbeg; k < kbeg + 640; k += 32){
        bf16x8 bfr = *(const bf16x8*)(bp + k);
        bf16x8 a[4];
        #pragma unroll
        for (int mt = 0; mt < 4; mt++) a[mt] = *(const bf16x8*)(ap[mt] + k);
        #pragma unroll
        for (int mt = 0; mt < 4; mt++)
            acc[mt] = __builtin_amdgcn_mfma_f32_16x16x32_bf16(a[mt], bfr, acc[mt], 0, 0, 0);
    }
    if (wid >= 2){
        #pragma unroll
        for (int mt = 0; mt < 4; mt++)
            #pragma unroll
            for (int r = 0; r < 4; r++)
                red4[wid-2][mt*16 + quad*4 + r][mr] = acc[mt][r];
    }
    __syncthreads();
    if (wid < 2){
        #pragma unroll
        for (int mt = 0; mt < 4; mt++)
            #pragma unroll
            for (int r = 0; r < 4; r++)
                acc[mt][r] += red4[wid][mt*16 + quad*4 + r][mr];
    }
    __syncthreads();
    if (wid == 1){
        #pragma unroll
        for (int mt = 0; mt < 4; mt++)
            #pragma unroll
            for (int r = 0; r < 4; r++)
                red4[0][mt*16 + quad*4 + r][mr] = acc[mt][r];
    }
    __syncthreads();
    if (wid == 0){
        float bv = bias[n0 + mr];
        #pragma unroll
        for (int mt = 0; mt < 4; mt++){
            #pragma unroll
            for (int r = 0; r < 4; r++){
                int m = mt*16 + quad*4 + r;
                float ge = gE[(size_t)m*2048 + n0 + mr];
                red4[0][m][mr] = acc[mt][r] + red4[0][m][mr] + bv + ge;  // same-lane RW: safe
            }
        }
    }
    __syncthreads();
    {
        int m = threadIdx.x & 63, jl = threadIdx.x >> 6;
        int j = blockIdx.x*4 + jl;
        float gi = sigmoidf_(red4[0][m][4*jl + 0]);
        float gf = sigmoidf_(red4[0][m][4*jl + 1]);
        float gv = tanhf(red4[0][m][4*jl + 2]);
        float go = sigmoidf_(red4[0][m][4*jl + 3]);
        float cc = c_state[m*512 + j];
        float cn = gf*cc + gi*gv;
        float hn = go * tanhf(cn);
        c_state[m*512 + j] = cn;
        h_next[m*512 + j] = __float2bfloat16(hn);
    }
}

// ================= batched preds GEMM, XCD-swizzled =================
// 1D grid 3776 = 8 XCD-groups x 59 n-tiles x 8 m-supertiles.
// q = id&7 selects XCD (round-robin dispatch); each XCD owns 59 n-tiles (3.8 MB of W <= 4 MB L2);
// the 8 m-supertile blocks of one n-tile are consecutive on that XCD -> W tile fetched once.
__global__ __launch_bounds__(256)
void preds_batched(const bf16_t* __restrict__ Ah, const bf16_t* __restrict__ W,
                   const float* __restrict__ bias, float* __restrict__ C,
                   const int* __restrict__ dec_len)
{
    const int id = blockIdx.x;
    const int q = id & 7;
    const int r = id >> 3;
    const int vy = q*59 + (r >> 3);   // n-tile 0..471 (469..471 are pad, fully guarded)
    const int vx = r & 7;             // m-supertile 0..7

    const int lane = threadIdx.x & 63;
    const int wave = threadIdx.x >> 6;
    const int mr = lane & 15;
    const int quad = lane >> 4;
    const int m0 = vx * 256 + wave * 64;
    const int n0 = vy * 64;

    const bf16_t* ap[4];
    const bf16_t* bp[4];
    #pragma unroll
    for (int i = 0; i < 4; i++){
        int row = m0 + i*16 + mr; if (row > 1855) row = 1855;
        ap[i] = Ah + (size_t)row*512 + quad*8;
        int n = n0 + i*16 + mr;   if (n > Vq-1) n = Vq-1;
        bp[i] = W + (size_t)n*512 + quad*8;
    }
    f32x4 zero = {0.f,0.f,0.f,0.f};
    f32x4 acc[4][4];
    #pragma unroll
    for (int i = 0; i < 4; i++)
        #pragma unroll
        for (int j = 0; j < 4; j++) acc[i][j] = zero;

    #pragma unroll
    for (int kk = 0; kk < 16; kk++){
        bf16x8 a[4], b[4];
        #pragma unroll
        for (int mt = 0; mt < 4; mt++) a[mt] = *(const bf16x8*)(ap[mt] + kk*32);
        #pragma unroll
        for (int nt = 0; nt < 4; nt++) b[nt] = *(const bf16x8*)(bp[nt] + kk*32);
        #pragma unroll
        for (int mt = 0; mt < 4; mt++)
            #pragma unroll
            for (int nt = 0; nt < 4; nt++)
                acc[mt][nt] = __builtin_amdgcn_mfma_f32_16x16x32_bf16(b[nt], a[mt], acc[mt][nt], 0, 0, 0);
    }

    // swapped-operand D layout: lane col (mr) = m, quad*4+r = n offset -> float4 stores
    #pragma unroll
    for (int mt = 0; mt < 4; mt++){
        int m = m0 + mt*16 + mr;
        if (m >= 1856) continue;
        int tt = m >> 6, b = m & 63;
        bool msk = (tt >= dec_len[b]);
        float* crow = C + (size_t)b*(Tq*Vq) + (size_t)tt*Vq;
        #pragma unroll
        for (int nt = 0; nt < 4; nt++){
            int n = n0 + nt*16 + quad*4;
            if (n < Vq){
                float4 bv = *(const float4*)(bias + n);
                f32x4 v = acc[mt][nt];
                float4 o;
                o.x = msk ? 0.f : (v[0] + bv.x);
                o.y = msk ? 0.f : (v[1] + bv.y);
                o.z = msk ? 0.f : (v[2] + bv.z);
                o.w = msk ? 0.f : (v[3] + bv.w);
                *(float4*)(crow + n) = o;
            }
        }
    }
}

extern "C" void kernel_launch(void* const* d_in, const int* in_sizes, int n_in,
                              void* d_out, int out_size, void* d_ws, size_t ws_size,
                              hipStream_t stream)
{
    const float* encoder_out = (const float*)d_in[0];
    const float* enc_att_w   = (const float*)d_in[1];
    const float* enc_att_b   = (const float*)d_in[2];
    const float* dec_att_w   = (const float*)d_in[3];
    const float* dec_att_b   = (const float*)d_in[4];
    const float* full_att_w  = (const float*)d_in[5];
    const float* full_att_b  = (const float*)d_in[6];
    const float* embed       = (const float*)d_in[7];
    const float* W_ih        = (const float*)d_in[8];
    const float* W_hh        = (const float*)d_in[9];
    const float* b_ih        = (const float*)d_in[10];
    const float* b_hh        = (const float*)d_in[11];
    const float* init_h_w    = (const float*)d_in[12];
    const float* init_h_b    = (const float*)d_in[13];
    const float* init_c_w    = (const float*)d_in[14];
    const float* init_c_b    = (const float*)d_in[15];
    const float* f_beta_w    = (const float*)d_in[16];
    const float* f_beta_b    = (const float*)d_in[17];
    const float* fc_w        = (const float*)d_in[18];
    const float* fc_b        = (const float*)d_in[19];
    const int*   enc_caps    = (const int*)d_in[20];
    const int*   cap_len     = (const int*)d_in[21];

    float* out_preds   = (float*)d_out;
    float* out_caps    = out_preds + (size_t)Bq*Tq*Vq;
    float* out_declen  = out_caps + Bq*Lq;
    float* out_alphas  = out_declen + Bq;
    float* out_sortind = out_alphas + (size_t)Bq*Tq*Pq;

    char* cur = (char*)d_ws;
    auto alloc = [&](size_t bytes) -> char* {
        char* p = cur;
        cur += (bytes + 255) & ~(size_t)255;
        return p;
    };
    bf16_t* enc_bf    = (bf16_t*)alloc((size_t)12544*2048*2);
    bf16_t* att1_bf   = (bf16_t*)alloc((size_t)12544*512*2);
    bf16_t* fcw_bf    = (bf16_t*)alloc((size_t)30000*512*2);
    bf16_t* wcatg_bf  = (bf16_t*)alloc((size_t)2048*2560*2);
    bf16_t* wembg_bf  = (bf16_t*)alloc((size_t)2048*512*2);
    bf16_t* embA_bf   = (bf16_t*)alloc((size_t)1856*512*2);
    float*  gatesE    = (float*)alloc((size_t)1856*2048*4);
    bf16_t* whc_bf    = (bf16_t*)alloc((size_t)1024*2048*2);
    bf16_t* wcat2_bf  = (bf16_t*)alloc((size_t)2560*512*2);
    bf16_t* encattw_bf= (bf16_t*)alloc((size_t)512*2048*2);
    bf16_t* meanenc_bf= (bf16_t*)alloc((size_t)64*2048*2);
    bf16_t* h_hist    = (bf16_t*)alloc((size_t)30*64*512*2);   // slot 0 = h0, slot t+1 = h after step t
    bf16_t* xcat2_bf  = (bf16_t*)alloc((size_t)64*2560*2);
    float* c_state   = (float*)alloc((size_t)64*512*4);
    float* att2gate  = (float*)alloc((size_t)64*2560*4);
    float* bias_hc   = (float*)alloc(1024*4);
    float* bias2     = (float*)alloc(2560*4);
    float* bias_g    = (float*)alloc(2048*4);
    int* caps_sorted = (int*)alloc(Bq*Lq*4);
    int* sort_ind_i  = (int*)alloc(64*4);
    int* dec_len_i   = (int*)alloc(64*4);

    // ---- setup ----
    sort_kernel<<<1, 64, 0, stream>>>(cap_len, enc_caps, sort_ind_i, dec_len_i,
                                      caps_sorted, out_caps, out_declen, out_sortind);

    cvt_bf16<<<(1048576+255)/256, 256, 0, stream>>>(encattw_bf, enc_att_w, 1048576);
    cvt_bf16<<<(15360000+255)/256, 256, 0, stream>>>(fcw_bf, fc_w, 15360000);
    pack_rowcat_bf16<<<(2097152+255)/256, 256, 0, stream>>>(whc_bf, init_h_w, 1048576, init_c_w, 1048576);
    pack_rowcat_bf16<<<(1310720+255)/256, 256, 0, stream>>>(wcat2_bf, dec_att_w, 262144, f_beta_w, 1048576);
    pack_wcatg2<<<(2048*2560+255)/256, 256, 0, stream>>>(wcatg_bf, W_ih, W_hh);
    pack_wembg<<<(2048*512+255)/256, 256, 0, stream>>>(wembg_bf, W_ih);
    pack_rowcat_f32<<<(1024+255)/256, 256, 0, stream>>>(bias_hc, init_h_b, 512, init_c_b, 512);
    pack_rowcat_f32<<<(2560+255)/256, 256, 0, stream>>>(bias2, dec_att_b, 512, f_beta_b, 2048);
    biasg_perm_kernel<<<8, 256, 0, stream>>>(bias_g, b_ih, b_hh);

    // emb gather (needs sort) + precomputed emb-part of gates for all 29 steps
    gather_emb<<<1856, 256, 0, stream>>>(embed, caps_sorted, embA_bf);
    embg_gemm<<<dim3(29,8), 256, 0, stream>>>(embA_bf, wembg_bf, gatesE);

    gather_cvt_mean<<<dim3(64,8), 256, 0, stream>>>(encoder_out, sort_ind_i, enc_bf, meanenc_bf);

    // h0/c0: M=64, N=1024, K=2048
    hc0_ksplit<<<16, 256, 0, stream>>>(meanenc_bf, whc_bf, bias_hc, h_hist, c_state);

    // att1: M=12544 (sorted), N=512, K=2048
    att1_gemm<<<dim3(196,2), 256, 0, stream>>>(enc_bf, encattw_bf, enc_att_b, att1_bf);

    for (int t = 0; t < Tq; t++){
        const bf16_t* h_prev = h_hist + (size_t)t*Bq*Hq;
        bf16_t* h_next = h_hist + (size_t)(t+1)*Bq*Hq;

        attg_gemm<<<40, 256, 0, stream>>>(h_prev, wcat2_bf, bias2, att2gate);

        awe_attn<<<dim3(64,4), 512, 0, stream>>>(att1_bf, att2gate, full_att_w, full_att_b,
                                                 dec_len_i, enc_bf, h_prev, out_alphas, xcat2_bf, t);

        gates_lstm2<<<128, 256, 0, stream>>>(xcat2_bf, wcatg_bf, bias_g,
                                             gatesE + (size_t)t*64*2048, c_state, h_next);
    }

    // batched preds over all 29 steps: M=1856, N=30000, K=512
    preds_batched<<<3776, 256, 0, stream>>>(h_hist + (size_t)Bq*Hq, fcw_bf, fc_b,
                                            out_preds, dec_len_i);
}